// Round 9
// baseline (518.296 us; speedup 1.0000x reference)
//
#include <hip/hip_runtime.h>
#include <cstdint>

// ---------------------------------------------------------------------------
// TemplateDeformNet on MI355X.
// R1: knn full-S LDS residency — 1 wave/SIMD, latency-bound (613 us).
// R2: split S into 4 chunks -> partial top-8 + merge (410 us, insert-bound).
// R3: sorted-insert + morton sort of template points (200 us knn_part).
// R4: surf morton sort — REGRESSED (848 us): spatial candidate order makes
//     monotone-improving runs; reverted in R8 (198 us, VALU 83% + LDS ~83%).
// R9: knn_part without LDS — candidates are wave-uniform, so read them via
//     uniform (scalar-path) loads straight into the FMA operands. Frees the
//     LDS pipe (393k cyc/CU), drops staging+barriers, and allows NCHUNK=2
//     (4096-cand chunks): 1.8x fewer top-8 insert events (the VALU cost).
// ---------------------------------------------------------------------------

#define T_PTS 16384
#define S_PTS 8192
#define B_SZ 4
#define D_FEAT 256
#define G_FEAT 512
#define M_ROWS (B_SZ * T_PTS) /* 65536 */
#define K1 320
#define N1 384
#define DISP_SZ (M_ROWS * 3)
#define NCHUNK 2
#define CHUNK_S (S_PTS / NCHUNK) /* 4096 */
#define NPLANE (NCHUNK * 8)      /* 16 */
#define NCELL 32768              /* 32^3 morton cells */

using u16 = unsigned short;
typedef short bf16x8 __attribute__((ext_vector_type(8)));
typedef float f32x4 __attribute__((ext_vector_type(4)));

__device__ __forceinline__ u16 f2bf(float f) {
  uint32_t x = __builtin_bit_cast(uint32_t, f);
  x += 0x7fffu + ((x >> 16) & 1u);  // RNE
  return (u16)(x >> 16);
}
__device__ __forceinline__ float bf2f(u16 h) {
  uint32_t x = ((uint32_t)h) << 16;
  return __builtin_bit_cast(float, x);
}
__device__ __forceinline__ void gload16(void* lds, const void* g) {
  __builtin_amdgcn_global_load_lds(
      (const __attribute__((address_space(1))) unsigned int*)g,
      (__attribute__((address_space(3))) unsigned int*)lds, 16, 0, 0);
}

// --------------------------- prep kernels ----------------------------------

__global__ __launch_bounds__(256) void prep_surf(const float* __restrict__ sxyz,
                                                 float4* __restrict__ surfp) {
  int i = blockIdx.x * 256 + threadIdx.x;  // B*S = 32768
  float x = sxyz[(size_t)i * 3], y = sxyz[(size_t)i * 3 + 1], z = sxyz[(size_t)i * 3 + 2];
  float4 v;
  v.x = x; v.y = y; v.z = z; v.w = fmaf(x, x, fmaf(y, y, z * z));
  surfp[i] = v;
}

// w1t: [384][320] bf16  (n<256: disp head dw1, n>=256: material mw1)
//      k<256 -> local (orig row 3+k); k in 256..258 -> template; else 0
// w2t: [256][256] bf16 = dw2^T ; w2bt: [64][128] bf16 = mw2^T
__global__ __launch_bounds__(256) void prep_w(
    const float* __restrict__ dw1, const float* __restrict__ mw1,
    const float* __restrict__ dw2, const float* __restrict__ mw2,
    u16* __restrict__ w1t, u16* __restrict__ w2t, u16* __restrict__ w2bt) {
  int i = blockIdx.x * 256 + threadIdx.x;  // 196608 total
  if (i < 122880) {
    int n = i / 320, k = i % 320;
    float v = 0.f;
    if (k < 256)      v = (n < 256) ? dw1[(size_t)(3 + k) * 256 + n] : mw1[(size_t)(3 + k) * 128 + (n - 256)];
    else if (k < 259) v = (n < 256) ? dw1[(size_t)(k - 256) * 256 + n] : mw1[(size_t)(k - 256) * 128 + (n - 256)];
    w1t[i] = f2bf(v);
  } else if (i < 188416) {
    int j = i - 122880;
    int n = j >> 8, k = j & 255;
    w2t[j] = f2bf(dw2[(size_t)k * 256 + n]);
  } else {
    int j = i - 188416;
    int n = j >> 7, k = j & 127;
    w2bt[j] = f2bf(mw2[(size_t)k * 64 + n]);
  }
}

// bias1[b][n] = base_bias[n] + sum_k gf[b][k]*W1[259+k][n]; grid (B,3), 512 thr,
// split-k=4 with LDS reduce (deterministic).
__global__ __launch_bounds__(512) void bias1_k(
    const float* __restrict__ gf, const float* __restrict__ dw1,
    const float* __restrict__ mw1, const float* __restrict__ db1,
    const float* __restrict__ mb1, float* __restrict__ bias1) {
  __shared__ float red[512];
  int b = blockIdx.x, nc = blockIdx.y;
  int tn = threadIdx.x & 127, tk = threadIdx.x >> 7;
  int n = nc * 128 + tn;
  const float* g = gf + b * G_FEAT;
  float s = 0.f;
  if (n < 256) {
    for (int k = tk * 128; k < tk * 128 + 128; k++)
      s = fmaf(g[k], dw1[(size_t)(259 + k) * 256 + n], s);
  } else {
    for (int k = tk * 128; k < tk * 128 + 128; k++)
      s = fmaf(g[k], mw1[(size_t)(259 + k) * 128 + (n - 256)], s);
  }
  red[threadIdx.x] = s;
  __syncthreads();
  if (tk == 0) {
    float base = (n < 256) ? db1[n] : mb1[n - 256];
    bias1[b * N1 + n] = base + ((red[tn] + red[tn + 128]) + (red[tn + 256] + red[tn + 384]));
  }
}

// --------------------- morton counting sort of template --------------------

__device__ __forceinline__ int spread5(int v) {
  return (v & 1) | ((v & 2) << 2) | ((v & 4) << 4) | ((v & 8) << 6) | ((v & 16) << 8);
}
__device__ __forceinline__ int morton15(float x, float y, float z) {
  int ix = (int)fminf(31.f, fmaxf(0.f, (x + 4.f) * 4.f));
  int iy = (int)fminf(31.f, fmaxf(0.f, (y + 4.f) * 4.f));
  int iz = (int)fminf(31.f, fmaxf(0.f, (z + 4.f) * 4.f));
  return (spread5(ix) << 2) | (spread5(iy) << 1) | spread5(iz);
}

__global__ __launch_bounds__(256) void zbins_k(int* __restrict__ bins) {
  bins[blockIdx.x * 256 + threadIdx.x] = 0;  // grid 512 -> B_SZ*NCELL
}

__global__ __launch_bounds__(256) void hist_t_k(const float* __restrict__ tmpl,
                                                int* __restrict__ bins_t,
                                                int* __restrict__ cellb) {
  int i = blockIdx.x * 256 + threadIdx.x;  // 65536
  int b = i >> 14;
  int c = morton15(tmpl[(size_t)i * 3], tmpl[(size_t)i * 3 + 1], tmpl[(size_t)i * 3 + 2]);
  cellb[i] = c;
  atomicAdd(&bins_t[b * NCELL + c], 1);
}

// exclusive prefix over NCELL bins per batch; grid B_SZ x 1024 threads.
__global__ __launch_bounds__(1024) void scan_k(int* __restrict__ bins) {
  __shared__ int sd[2048];
  int* bb = bins + blockIdx.x * NCELL;
  int tid = threadIdx.x;
  int running = 0;
  for (int c = 0; c < NCELL / 1024; ++c) {
    int v = bb[c * 1024 + tid];
    sd[tid] = v;
    __syncthreads();
    int cur = 0;
#pragma unroll
    for (int s = 0; s < 10; ++s) {
      int off = 1 << s;
      int val = sd[cur * 1024 + tid] + ((tid >= off) ? sd[cur * 1024 + tid - off] : 0);
      sd[(1 - cur) * 1024 + tid] = val;
      __syncthreads();
      cur ^= 1;
    }
    int incl = sd[cur * 1024 + tid];
    bb[c * 1024 + tid] = running + incl - v;
    running += sd[cur * 1024 + 1023];
    __syncthreads();
  }
}

__global__ __launch_bounds__(256) void scatter_t_k(const float* __restrict__ tmpl,
                                                   const int* __restrict__ cellb,
                                                   int* __restrict__ bins_t,
                                                   int* __restrict__ perm,
                                                   float4* __restrict__ tmplS) {
  int i = blockIdx.x * 256 + threadIdx.x;  // 65536
  int b = i >> 14, t = i & 16383;
  int pos = atomicAdd(&bins_t[b * NCELL + cellb[i]], 1);
  int dst = (b << 14) + pos;
  perm[dst] = t;
  float4 v;
  v.x = tmpl[(size_t)i * 3]; v.y = tmpl[(size_t)i * 3 + 1]; v.z = tmpl[(size_t)i * 3 + 2];
  v.w = 0.f;
  tmplS[dst] = v;
}

// ------------------------------- KNN ---------------------------------------
// No LDS: the candidate stream is wave-uniform, so groups of 8 candidates are
// loaded through the scalar/uniform path (register double-buffer) and feed
// the per-lane FMAs directly. Partial top-8 per (sorted query, chunk of
// 4096); sorted-ascending list, min-of-8 gate, strict-< shift-insert (scan
// order = index order -> reference tie semantics).
__global__ __launch_bounds__(256) void knn_part_k(const float4* __restrict__ surfp,
                                                  const float4* __restrict__ tmplS,
                                                  float* __restrict__ part_d,
                                                  int* __restrict__ part_i) {
  const int ch = blockIdx.y, b = blockIdx.z;
  const int t = (blockIdx.x << 8) + threadIdx.x;  // sorted query position
  const int gi = b * T_PTS + t;

  const float4* sp = surfp + (size_t)b * S_PTS + ch * CHUNK_S;

  float4 tp = tmplS[gi];
  float nx = -2.f * tp.x, ny = -2.f * tp.y, nz = -2.f * tp.z;
  float tsq = fmaf(tp.x, tp.x, fmaf(tp.y, tp.y, tp.z * tp.z));

  float dd[8]; int ii[8];
#pragma unroll
  for (int q = 0; q < 8; q++) { dd[q] = 3e38f; ii[q] = 0; }
  float worst = 3e38f;

  auto proc = [&](const float4* c, int base) {
    float d2[8];
#pragma unroll
    for (int q = 0; q < 8; q++)
      d2[q] = fmaf(nx, c[q].x, fmaf(ny, c[q].y, fmaf(nz, c[q].z, tsq + c[q].w)));
    float m = fminf(fminf(fminf(d2[0], d2[1]), fminf(d2[2], d2[3])),
                    fminf(fminf(d2[4], d2[5]), fminf(d2[6], d2[7])));
    while (m < worst) {
      // argmin (lowest index on within-group tie)
      int qi = 7;
#pragma unroll
      for (int q = 6; q >= 0; --q) qi = (d2[q] == m) ? q : qi;
      int gx = base + qi;
      // shift-insert (m, gx) into sorted-ascending list; strict < keeps
      // earlier (lower-index) entries ahead of equal later ones.
#pragma unroll
      for (int r = 7; r >= 1; --r) {
        bool cr = m < dd[r], cr1 = m < dd[r - 1];
        dd[r] = cr ? (cr1 ? dd[r - 1] : m) : dd[r];
        ii[r] = cr ? (cr1 ? ii[r - 1] : gx) : ii[r];
      }
      bool c0 = m < dd[0];
      dd[0] = c0 ? m : dd[0];
      ii[0] = c0 ? gx : ii[0];
      worst = dd[7];
#pragma unroll
      for (int q = 0; q < 8; ++q) d2[q] = (q == qi) ? 3e38f : d2[q];
      m = fminf(fminf(fminf(d2[0], d2[1]), fminf(d2[2], d2[3])),
                fminf(fminf(d2[4], d2[5]), fminf(d2[6], d2[7])));
    }
  };

  float4 ca[8], cb[8];
#pragma unroll
  for (int q = 0; q < 8; q++) ca[q] = sp[q];

  constexpr int NG = CHUNK_S / 8;  // 512, even
  for (int g = 0; g < NG; g += 2) {
#pragma unroll
    for (int q = 0; q < 8; q++) cb[q] = sp[(g + 1) * 8 + q];
    proc(ca, g * 8);
#pragma unroll
    for (int q = 0; q < 8; q++) ca[q] = sp[((g + 2) & (NG - 1)) * 8 + q];  // wraps last iter
    proc(cb, (g + 1) * 8);
  }

#pragma unroll
  for (int q = 0; q < 8; q++) {
    part_d[(size_t)(ch * 8 + q) * M_ROWS + gi] = dd[q];
    part_i[(size_t)(ch * 8 + q) * M_ROWS + gi] = ii[q] + ch * CHUNK_S;
  }
}

// Merge NPLANE partial lists -> final top-8 by lex (d2, idx), matching
// lax.top_k stable tie order; rows stay in sorted order (knn[sorted]).
__global__ __launch_bounds__(256) void knn_merge_k(const float* __restrict__ part_d,
                                                   const int* __restrict__ part_i,
                                                   int* __restrict__ knn) {
  int pt = blockIdx.x * 256 + threadIdx.x;  // sorted global index
  float d[NPLANE]; int x[NPLANE];
#pragma unroll
  for (int q = 0; q < NPLANE; q++) {
    d[q] = part_d[(size_t)q * M_ROWS + pt];
    x[q] = part_i[(size_t)q * M_ROWS + pt];
  }
#pragma unroll
  for (int s = 0; s < 8; s++) {
    float bd = d[0]; int bx = x[0]; int bp = 0;
#pragma unroll
    for (int q = 1; q < NPLANE; q++) {
      bool lt = (d[q] < bd) || (d[q] == bd && x[q] < bx);
      bd = lt ? d[q] : bd;
      bx = lt ? x[q] : bx;
      bp = lt ? q : bp;
    }
    knn[(size_t)pt * 8 + s] = bx;
#pragma unroll
    for (int q = 0; q < NPLANE; q++)
      if (q == bp) d[q] = 3e38f;
  }
}

// --------------------------- gather + x assembly ---------------------------
// One wave per sorted row; adjacent rows share neighbors -> L2 reuse.
__global__ __launch_bounds__(256) void gather_k(const int* __restrict__ knn,
                                                const float* __restrict__ pf,
                                                const float4* __restrict__ tmplS,
                                                u16* __restrict__ xb) {
  int m = blockIdx.x * 4 + (threadIdx.x >> 6);
  int lane = threadIdx.x & 63;
  int b = m >> 14;  // T = 16384
  const int* id = knn + (size_t)m * 8;
  const float* base = pf + (size_t)b * S_PTS * D_FEAT;
  float ax = 0, ay = 0, az = 0, aw = 0;
#pragma unroll
  for (int k = 0; k < 8; k++) {
    const float4* p = (const float4*)(base + (size_t)id[k] * D_FEAT) + lane;
    float4 v = *p;
    ax += v.x; ay += v.y; az += v.z; aw += v.w;
  }
  ushort4 o;
  o.x = f2bf(ax * 0.125f); o.y = f2bf(ay * 0.125f);
  o.z = f2bf(az * 0.125f); o.w = f2bf(aw * 0.125f);
  *(ushort4*)(xb + (size_t)m * K1 + lane * 4) = o;
  float4 tp = tmplS[m];
  float tv = (lane == 0) ? tp.x : (lane == 1) ? tp.y : (lane == 2) ? tp.z : 0.f;
  xb[(size_t)m * K1 + 256 + lane] = f2bf(tv);  // cols 256..319 (3 tmpl + 61 pad)
}

// ------------------------------- GEMM --------------------------------------
// bf16 MFMA 16x16x32, BK=64, global_load_lds staging with T2 XOR swizzle.
template <int BM, int BN>
__global__ __launch_bounds__(256) void gemm_k(const u16* __restrict__ X, int ldx,
                                              const u16* __restrict__ Wt,
                                              const float* __restrict__ bias, int bstride,
                                              u16* __restrict__ Y, int ldy, int K) {
  constexpr int WM = 2, WN = 2;
  constexpr int FM = BM / WM / 16, FN = BN / WN / 16;
  __shared__ u16 As[BM * 64];
  __shared__ u16 Bs[BN * 64];
  const int tid = threadIdx.x, lane = tid & 63, wid = tid >> 6;
  const int m0 = blockIdx.x * BM, n0 = blockIdx.y * BN;
  const int wm0 = (wid / WN) * (BM / WM), wn0 = (wid % WN) * (BN / WN);

  f32x4 acc[FM][FN] = {};

  for (int kt = 0; kt < K; kt += 64) {
#pragma unroll
    for (int i = 0; i < BM * 8 / 256; i++) {
      int c = i * 256 + tid;
      int r = c >> 3, s = c & 7;
      int ss = s ^ (r & 7);  // pre-swizzled source, linear LDS dest
      gload16(As + c * 8, X + (size_t)(m0 + r) * ldx + kt + ss * 8);
    }
#pragma unroll
    for (int i = 0; i < BN * 8 / 256; i++) {
      int c = i * 256 + tid;
      int r = c >> 3, s = c & 7;
      int ss = s ^ (r & 7);
      gload16(Bs + c * 8, Wt + (size_t)(n0 + r) * K + kt + ss * 8);
    }
    __syncthreads();
#pragma unroll
    for (int kk = 0; kk < 2; kk++) {
      bf16x8 af[FM], bfr[FN];
#pragma unroll
      for (int i = 0; i < FM; i++) {
        int r = wm0 + i * 16 + (lane & 15);
        int q = kk * 4 + (lane >> 4);
        af[i] = *(const bf16x8*)(As + r * 64 + ((q ^ (r & 7)) * 8));
      }
#pragma unroll
      for (int j = 0; j < FN; j++) {
        int r = wn0 + j * 16 + (lane & 15);
        int q = kk * 4 + (lane >> 4);
        bfr[j] = *(const bf16x8*)(Bs + r * 64 + ((q ^ (r & 7)) * 8));
      }
#pragma unroll
      for (int i = 0; i < FM; i++)
#pragma unroll
        for (int j = 0; j < FN; j++)
          acc[i][j] = __builtin_amdgcn_mfma_f32_16x16x32_bf16(af[i], bfr[j], acc[i][j], 0, 0, 0);
    }
    __syncthreads();
  }

  const float* brow = bias + (size_t)(m0 / T_PTS) * bstride;
#pragma unroll
  for (int i = 0; i < FM; i++)
#pragma unroll
    for (int j = 0; j < FN; j++)
#pragma unroll
      for (int r = 0; r < 4; r++) {
        int rl = wm0 + i * 16 + (lane >> 4) * 4 + r;
        int cl = wn0 + j * 16 + (lane & 15);
        float v = acc[i][j][r] + brow[n0 + cl];
        v = fmaxf(v, 0.f);
        Y[(size_t)(m0 + rl) * ldy + n0 + cl] = f2bf(v);
      }
}

// ----------------------------- final heads ---------------------------------
// Rows arrive sorted; scatter to original order via perm.
__global__ __launch_bounds__(256) void final_k(const u16* __restrict__ h2,
                                               const u16* __restrict__ m2,
                                               const float* __restrict__ dw3,
                                               const float* __restrict__ db3,
                                               const float* __restrict__ mw3,
                                               const float* __restrict__ mb3,
                                               const int* __restrict__ perm,
                                               float* __restrict__ out) {
  int m = blockIdx.x * 4 + (threadIdx.x >> 6);
  int lane = threadIdx.x & 63;
  ushort4 hv = *(const ushort4*)(h2 + (size_t)m * 256 + lane * 4);
  float hq[4] = {bf2f(hv.x), bf2f(hv.y), bf2f(hv.z), bf2f(hv.w)};
  float a0 = 0, a1 = 0, a2 = 0, am = 0;
#pragma unroll
  for (int q = 0; q < 4; q++) {
    int k = lane * 4 + q;
    a0 = fmaf(hq[q], dw3[(size_t)k * 3 + 0], a0);
    a1 = fmaf(hq[q], dw3[(size_t)k * 3 + 1], a1);
    a2 = fmaf(hq[q], dw3[(size_t)k * 3 + 2], a2);
  }
  if (lane < 16) {
    ushort4 mv = *(const ushort4*)(m2 + (size_t)m * 64 + lane * 4);
    float mq[4] = {bf2f(mv.x), bf2f(mv.y), bf2f(mv.z), bf2f(mv.w)};
#pragma unroll
    for (int q = 0; q < 4; q++) am = fmaf(mq[q], mw3[lane * 4 + q], am);
  }
#pragma unroll
  for (int off = 32; off > 0; off >>= 1) {
    a0 += __shfl_down(a0, off);
    a1 += __shfl_down(a1, off);
    a2 += __shfl_down(a2, off);
    am += __shfl_down(am, off);
  }
  if (lane == 0) {
    int b = m >> 14;
    int orig = (b << 14) + perm[m];
    out[(size_t)orig * 3 + 0] = a0 + db3[0];
    out[(size_t)orig * 3 + 1] = a1 + db3[1];
    out[(size_t)orig * 3 + 2] = a2 + db3[2];
    float s = am + mb3[0];
    out[DISP_SZ + orig] = 1.f / (1.f + expf(-s));
  }
}

// ------------------------------ launcher -----------------------------------

extern "C" void kernel_launch(void* const* d_in, const int* in_sizes, int n_in,
                              void* d_out, int out_size, void* d_ws, size_t ws_size,
                              hipStream_t stream) {
  const float* tmpl = (const float*)d_in[0];
  const float* sxyz = (const float*)d_in[1];
  const float* gf   = (const float*)d_in[2];
  const float* pf   = (const float*)d_in[3];
  const float* dw1  = (const float*)d_in[4];
  const float* db1  = (const float*)d_in[5];
  const float* dw2  = (const float*)d_in[6];
  const float* db2  = (const float*)d_in[7];
  const float* dw3  = (const float*)d_in[8];
  const float* db3  = (const float*)d_in[9];
  const float* mw1  = (const float*)d_in[10];
  const float* mb1  = (const float*)d_in[11];
  const float* mw2  = (const float*)d_in[12];
  const float* mb2  = (const float*)d_in[13];
  const float* mw3  = (const float*)d_in[14];
  const float* mb3  = (const float*)d_in[15];

  char* ws = (char*)d_ws;
  float4* surfp  = (float4*)(ws + 0);           //   524288 B [4][8192]
  int*    knn    = (int*)(ws + 524288);         //  2097152 B [65536][8]
  u16*    xb     = (u16*)(ws + 2621440);        // 41943040 B [65536][320]
  // alias xb (dead until gather_k):
  float*  part_d = (float*)(ws + 2621440);      //  4194304 B [16][65536]
  int*    part_i = (int*)(ws + 11010048);       //  4194304 B [16][65536]
  u16*    w1t    = (u16*)(ws + 44564480);       //   245760 B [384][320]
  u16*    w2t    = (u16*)(ws + 44810240);       //   131072 B [256][256]
  u16*    w2bt   = (u16*)(ws + 44941312);       //    16384 B [64][128]
  float*  bias1  = (float*)(ws + 44957696);     //     6144 B [4][384]
  u16*    h1     = (u16*)(ws + 44963840);       // 50331648 B [65536][384]
  // alias h1 (dead until gemm1; all consumed by scatter/knn/gather):
  int*    cellb  = (int*)(ws + 44963840);       //   262144 B [65536]
  int*    bins   = (int*)(ws + 45225984);       //   524288 B [4][32768]
  float4* tmplS  = (float4*)(ws + 45750272);    //  1048576 B [65536]
  u16*    h2     = (u16*)(ws + 95295488);       // 33554432 B [65536][256]
  u16*    m2     = (u16*)(ws + 128849920);      //  8388608 B [65536][64]
  int*    perm   = (int*)(ws + 137238528);      //   262144 B [65536]
  float*  out    = (float*)d_out;

  prep_surf<<<128, 256, 0, stream>>>(sxyz, surfp);
  prep_w<<<768, 256, 0, stream>>>(dw1, mw1, dw2, mw2, w1t, w2t, w2bt);
  bias1_k<<<dim3(B_SZ, 3), 512, 0, stream>>>(gf, dw1, mw1, db1, mb1, bias1);
  zbins_k<<<512, 256, 0, stream>>>(bins);
  hist_t_k<<<256, 256, 0, stream>>>(tmpl, bins, cellb);
  scan_k<<<B_SZ, 1024, 0, stream>>>(bins);
  scatter_t_k<<<256, 256, 0, stream>>>(tmpl, cellb, bins, perm, tmplS);
  knn_part_k<<<dim3(64, NCHUNK, B_SZ), 256, 0, stream>>>(surfp, tmplS, part_d, part_i);
  knn_merge_k<<<256, 256, 0, stream>>>(part_d, part_i, knn);
  gather_k<<<16384, 256, 0, stream>>>(knn, pf, tmplS, xb);
  gemm_k<128, 128><<<dim3(512, 3), 256, 0, stream>>>(xb, K1, w1t, bias1, N1, h1, N1, K1);
  gemm_k<128, 128><<<dim3(512, 2), 256, 0, stream>>>(h1, N1, w2t, db2, 0, h2, 256, 256);
  gemm_k<128, 64><<<dim3(512, 1), 256, 0, stream>>>(h1 + 256, N1, w2bt, mb2, 0, m2, 64, 128);
  final_k<<<16384, 256, 0, stream>>>(h2, m2, dw3, db3, mw3, mb3, perm, out);
}

// Round 10
// 423.905 us; speedup vs baseline: 1.2227x; 1.2227x over previous
//
#include <hip/hip_runtime.h>
#include <cstdint>

// ---------------------------------------------------------------------------
// TemplateDeformNet on MI355X.
// R1: knn full-S LDS residency — 1 wave/SIMD, latency-bound (613 us).
// R2: split S -> partial top-8 + merge (410 us, insert-bound).
// R3: sorted-insert + morton sort of template points (200 us knn_part).
// R4: surf morton sort — REGRESSED (848 us); reverted (R8: 198 us).
// R9: LDS-free scalar-path knn — still 199 us: latency-bound at 2 waves/SIMD;
//     wave-any insert amplification is the floor (P(any lane)≈1 per group).
// R10: (a) insert body without argmin/clear/re-min: per-candidate in-index-
//      order gated shift-insert (~25 instr/winner vs ~60) — same semantics.
//      (b) NCHUNK=4 -> 4 blocks/CU (latency hiding back).
//      (c) scan_k -> 64-block local scan + segment-base pass (was 4-block
//      serial Hillis-Steele).
// ---------------------------------------------------------------------------

#define T_PTS 16384
#define S_PTS 8192
#define B_SZ 4
#define D_FEAT 256
#define G_FEAT 512
#define M_ROWS (B_SZ * T_PTS) /* 65536 */
#define K1 320
#define N1 384
#define DISP_SZ (M_ROWS * 3)
#define NCHUNK 4
#define CHUNK_S (S_PTS / NCHUNK) /* 2048 */
#define NPLANE (NCHUNK * 8)      /* 32 */
#define NCELL 32768              /* 32^3 morton cells */

using u16 = unsigned short;
typedef short bf16x8 __attribute__((ext_vector_type(8)));
typedef float f32x4 __attribute__((ext_vector_type(4)));

__device__ __forceinline__ u16 f2bf(float f) {
  uint32_t x = __builtin_bit_cast(uint32_t, f);
  x += 0x7fffu + ((x >> 16) & 1u);  // RNE
  return (u16)(x >> 16);
}
__device__ __forceinline__ float bf2f(u16 h) {
  uint32_t x = ((uint32_t)h) << 16;
  return __builtin_bit_cast(float, x);
}
__device__ __forceinline__ void gload16(void* lds, const void* g) {
  __builtin_amdgcn_global_load_lds(
      (const __attribute__((address_space(1))) unsigned int*)g,
      (__attribute__((address_space(3))) unsigned int*)lds, 16, 0, 0);
}

// --------------------------- prep kernels ----------------------------------

__global__ __launch_bounds__(256) void prep_surf(const float* __restrict__ sxyz,
                                                 float4* __restrict__ surfp) {
  int i = blockIdx.x * 256 + threadIdx.x;  // B*S = 32768
  float x = sxyz[(size_t)i * 3], y = sxyz[(size_t)i * 3 + 1], z = sxyz[(size_t)i * 3 + 2];
  float4 v;
  v.x = x; v.y = y; v.z = z; v.w = fmaf(x, x, fmaf(y, y, z * z));
  surfp[i] = v;
}

// w1t: [384][320] bf16  (n<256: disp head dw1, n>=256: material mw1)
//      k<256 -> local (orig row 3+k); k in 256..258 -> template; else 0
// w2t: [256][256] bf16 = dw2^T ; w2bt: [64][128] bf16 = mw2^T
__global__ __launch_bounds__(256) void prep_w(
    const float* __restrict__ dw1, const float* __restrict__ mw1,
    const float* __restrict__ dw2, const float* __restrict__ mw2,
    u16* __restrict__ w1t, u16* __restrict__ w2t, u16* __restrict__ w2bt) {
  int i = blockIdx.x * 256 + threadIdx.x;  // 196608 total
  if (i < 122880) {
    int n = i / 320, k = i % 320;
    float v = 0.f;
    if (k < 256)      v = (n < 256) ? dw1[(size_t)(3 + k) * 256 + n] : mw1[(size_t)(3 + k) * 128 + (n - 256)];
    else if (k < 259) v = (n < 256) ? dw1[(size_t)(k - 256) * 256 + n] : mw1[(size_t)(k - 256) * 128 + (n - 256)];
    w1t[i] = f2bf(v);
  } else if (i < 188416) {
    int j = i - 122880;
    int n = j >> 8, k = j & 255;
    w2t[j] = f2bf(dw2[(size_t)k * 256 + n]);
  } else {
    int j = i - 188416;
    int n = j >> 7, k = j & 127;
    w2bt[j] = f2bf(mw2[(size_t)k * 64 + n]);
  }
}

// bias1[b][n] = base_bias[n] + sum_k gf[b][k]*W1[259+k][n]; grid (B,3), 512 thr,
// split-k=4 with LDS reduce (deterministic).
__global__ __launch_bounds__(512) void bias1_k(
    const float* __restrict__ gf, const float* __restrict__ dw1,
    const float* __restrict__ mw1, const float* __restrict__ db1,
    const float* __restrict__ mb1, float* __restrict__ bias1) {
  __shared__ float red[512];
  int b = blockIdx.x, nc = blockIdx.y;
  int tn = threadIdx.x & 127, tk = threadIdx.x >> 7;
  int n = nc * 128 + tn;
  const float* g = gf + b * G_FEAT;
  float s = 0.f;
  if (n < 256) {
    for (int k = tk * 128; k < tk * 128 + 128; k++)
      s = fmaf(g[k], dw1[(size_t)(259 + k) * 256 + n], s);
  } else {
    for (int k = tk * 128; k < tk * 128 + 128; k++)
      s = fmaf(g[k], mw1[(size_t)(259 + k) * 128 + (n - 256)], s);
  }
  red[threadIdx.x] = s;
  __syncthreads();
  if (tk == 0) {
    float base = (n < 256) ? db1[n] : mb1[n - 256];
    bias1[b * N1 + n] = base + ((red[tn] + red[tn + 128]) + (red[tn + 256] + red[tn + 384]));
  }
}

// --------------------- morton counting sort of template --------------------

__device__ __forceinline__ int spread5(int v) {
  return (v & 1) | ((v & 2) << 2) | ((v & 4) << 4) | ((v & 8) << 6) | ((v & 16) << 8);
}
__device__ __forceinline__ int morton15(float x, float y, float z) {
  int ix = (int)fminf(31.f, fmaxf(0.f, (x + 4.f) * 4.f));
  int iy = (int)fminf(31.f, fmaxf(0.f, (y + 4.f) * 4.f));
  int iz = (int)fminf(31.f, fmaxf(0.f, (z + 4.f) * 4.f));
  return (spread5(ix) << 2) | (spread5(iy) << 1) | spread5(iz);
}

__global__ __launch_bounds__(256) void zbins_k(int* __restrict__ bins) {
  bins[blockIdx.x * 256 + threadIdx.x] = 0;  // grid 512 -> B_SZ*NCELL
}

__global__ __launch_bounds__(256) void hist_t_k(const float* __restrict__ tmpl,
                                                int* __restrict__ bins_t,
                                                int* __restrict__ cellb) {
  int i = blockIdx.x * 256 + threadIdx.x;  // 65536
  int b = i >> 14;
  int c = morton15(tmpl[(size_t)i * 3], tmpl[(size_t)i * 3 + 1], tmpl[(size_t)i * 3 + 2]);
  cellb[i] = c;
  atomicAdd(&bins_t[b * NCELL + c], 1);
}

// Local exclusive scan of 2048-bin segments; grid 64 x 1024 threads.
// bins become within-segment exclusive scans; segsum[seg] = segment total.
__global__ __launch_bounds__(1024) void scan1_k(int* __restrict__ bins,
                                                int* __restrict__ segsum) {
  __shared__ int sd[2048];
  int seg = blockIdx.x, tid = threadIdx.x;
  int* bb = bins + seg * 2048;
  int e0 = bb[2 * tid], e1 = bb[2 * tid + 1];
  sd[tid] = e0 + e1;
  __syncthreads();
  int cur = 0;
#pragma unroll
  for (int s = 0; s < 10; ++s) {
    int off = 1 << s;
    int val = sd[cur * 1024 + tid] + ((tid >= off) ? sd[cur * 1024 + tid - off] : 0);
    sd[(1 - cur) * 1024 + tid] = val;
    __syncthreads();
    cur ^= 1;
  }
  int incl = sd[cur * 1024 + tid];
  int excl = incl - (e0 + e1);
  bb[2 * tid] = excl;
  bb[2 * tid + 1] = excl + e0;
  if (tid == 1023) segsum[seg] = incl;
}

// Per-batch exclusive scan of the 16 segment totals (64 segs total, 1 block).
__global__ __launch_bounds__(64) void scan2_k(int* __restrict__ segsum) {
  __shared__ int tot[64];
  int tid = threadIdx.x;
  int b = tid >> 4, w = tid & 15;
  tot[tid] = segsum[tid];
  __syncthreads();
  int s = 0;
  for (int j = 0; j < 16; ++j) s += (j < w) ? tot[b * 16 + j] : 0;
  segsum[tid] = s;  // becomes per-batch segment base
}

__global__ __launch_bounds__(256) void scatter_t_k(const float* __restrict__ tmpl,
                                                   const int* __restrict__ cellb,
                                                   int* __restrict__ bins_t,
                                                   const int* __restrict__ segbase,
                                                   int* __restrict__ perm,
                                                   float4* __restrict__ tmplS) {
  int i = blockIdx.x * 256 + threadIdx.x;  // 65536
  int b = i >> 14, t = i & 16383;
  int idx = b * NCELL + cellb[i];
  int local = atomicAdd(&bins_t[idx], 1);
  int dst = (b << 14) + segbase[idx >> 11] + local;
  perm[dst] = t;
  float4 v;
  v.x = tmpl[(size_t)i * 3]; v.y = tmpl[(size_t)i * 3 + 1]; v.z = tmpl[(size_t)i * 3 + 2];
  v.w = 0.f;
  tmplS[dst] = v;
}

// ------------------------------- KNN ---------------------------------------
// LDS-free: candidate stream is wave-uniform (scalar loads, register double
// buffer). Partial top-8 per (sorted query, chunk of 2048). Sorted-ascending
// top-8; min-of-8 gate, then per-candidate IN INDEX ORDER gated shift-insert
// (strict < -> reference tie semantics; no argmin/clear/re-min bookkeeping).
__global__ __launch_bounds__(256) void knn_part_k(const float4* __restrict__ surfp,
                                                  const float4* __restrict__ tmplS,
                                                  float* __restrict__ part_d,
                                                  int* __restrict__ part_i) {
  const int ch = blockIdx.y, b = blockIdx.z;
  const int t = (blockIdx.x << 8) + threadIdx.x;  // sorted query position
  const int gi = b * T_PTS + t;

  const float4* sp = surfp + (size_t)b * S_PTS + ch * CHUNK_S;

  float4 tp = tmplS[gi];
  float nx = -2.f * tp.x, ny = -2.f * tp.y, nz = -2.f * tp.z;
  float tsq = fmaf(tp.x, tp.x, fmaf(tp.y, tp.y, tp.z * tp.z));

  float dd[8]; int ii[8];
#pragma unroll
  for (int q = 0; q < 8; q++) { dd[q] = 3e38f; ii[q] = 0; }
  float worst = 3e38f;

  auto proc = [&](const float4* c, int base) {
    float d2[8];
#pragma unroll
    for (int q = 0; q < 8; q++)
      d2[q] = fmaf(nx, c[q].x, fmaf(ny, c[q].y, fmaf(nz, c[q].z, tsq + c[q].w)));
    float m = fminf(fminf(fminf(d2[0], d2[1]), fminf(d2[2], d2[3])),
                    fminf(fminf(d2[4], d2[5]), fminf(d2[6], d2[7])));
    if (m < worst) {
#pragma unroll
      for (int q = 0; q < 8; ++q) {
        float v = d2[q];
        if (v < worst) {
          int gx = base + q;
          // shift-insert (v, gx) into sorted-ascending list; strict < keeps
          // earlier (lower-index) entries ahead of equal later ones.
#pragma unroll
          for (int r = 7; r >= 1; --r) {
            bool cr = v < dd[r], cr1 = v < dd[r - 1];
            dd[r] = cr ? (cr1 ? dd[r - 1] : v) : dd[r];
            ii[r] = cr ? (cr1 ? ii[r - 1] : gx) : ii[r];
          }
          bool c0 = v < dd[0];
          dd[0] = c0 ? v : dd[0];
          ii[0] = c0 ? gx : ii[0];
          worst = dd[7];
        }
      }
    }
  };

  float4 ca[8], cb[8];
#pragma unroll
  for (int q = 0; q < 8; q++) ca[q] = sp[q];

  constexpr int NG = CHUNK_S / 8;  // 256, even
  for (int g = 0; g < NG; g += 2) {
#pragma unroll
    for (int q = 0; q < 8; q++) cb[q] = sp[(g + 1) * 8 + q];
    proc(ca, g * 8);
#pragma unroll
    for (int q = 0; q < 8; q++) ca[q] = sp[((g + 2) & (NG - 1)) * 8 + q];  // wraps last iter
    proc(cb, (g + 1) * 8);
  }

#pragma unroll
  for (int q = 0; q < 8; q++) {
    part_d[(size_t)(ch * 8 + q) * M_ROWS + gi] = dd[q];
    part_i[(size_t)(ch * 8 + q) * M_ROWS + gi] = ii[q] + ch * CHUNK_S;
  }
}

// Merge NPLANE partial lists -> final top-8 by lex (d2, idx), matching
// lax.top_k stable tie order; rows stay in sorted order (knn[sorted]).
__global__ __launch_bounds__(256) void knn_merge_k(const float* __restrict__ part_d,
                                                   const int* __restrict__ part_i,
                                                   int* __restrict__ knn) {
  int pt = blockIdx.x * 256 + threadIdx.x;  // sorted global index
  float d[NPLANE]; int x[NPLANE];
#pragma unroll
  for (int q = 0; q < NPLANE; q++) {
    d[q] = part_d[(size_t)q * M_ROWS + pt];
    x[q] = part_i[(size_t)q * M_ROWS + pt];
  }
#pragma unroll
  for (int s = 0; s < 8; s++) {
    float bd = d[0]; int bx = x[0]; int bp = 0;
#pragma unroll
    for (int q = 1; q < NPLANE; q++) {
      bool lt = (d[q] < bd) || (d[q] == bd && x[q] < bx);
      bd = lt ? d[q] : bd;
      bx = lt ? x[q] : bx;
      bp = lt ? q : bp;
    }
    knn[(size_t)pt * 8 + s] = bx;
#pragma unroll
    for (int q = 0; q < NPLANE; q++)
      if (q == bp) d[q] = 3e38f;
  }
}

// --------------------------- gather + x assembly ---------------------------
// One wave per sorted row; adjacent rows share neighbors -> L2 reuse.
__global__ __launch_bounds__(256) void gather_k(const int* __restrict__ knn,
                                                const float* __restrict__ pf,
                                                const float4* __restrict__ tmplS,
                                                u16* __restrict__ xb) {
  int m = blockIdx.x * 4 + (threadIdx.x >> 6);
  int lane = threadIdx.x & 63;
  int b = m >> 14;  // T = 16384
  const int* id = knn + (size_t)m * 8;
  const float* base = pf + (size_t)b * S_PTS * D_FEAT;
  float ax = 0, ay = 0, az = 0, aw = 0;
#pragma unroll
  for (int k = 0; k < 8; k++) {
    const float4* p = (const float4*)(base + (size_t)id[k] * D_FEAT) + lane;
    float4 v = *p;
    ax += v.x; ay += v.y; az += v.z; aw += v.w;
  }
  ushort4 o;
  o.x = f2bf(ax * 0.125f); o.y = f2bf(ay * 0.125f);
  o.z = f2bf(az * 0.125f); o.w = f2bf(aw * 0.125f);
  *(ushort4*)(xb + (size_t)m * K1 + lane * 4) = o;
  float4 tp = tmplS[m];
  float tv = (lane == 0) ? tp.x : (lane == 1) ? tp.y : (lane == 2) ? tp.z : 0.f;
  xb[(size_t)m * K1 + 256 + lane] = f2bf(tv);  // cols 256..319 (3 tmpl + 61 pad)
}

// ------------------------------- GEMM --------------------------------------
// bf16 MFMA 16x16x32, BK=64, global_load_lds staging with T2 XOR swizzle.
template <int BM, int BN>
__global__ __launch_bounds__(256) void gemm_k(const u16* __restrict__ X, int ldx,
                                              const u16* __restrict__ Wt,
                                              const float* __restrict__ bias, int bstride,
                                              u16* __restrict__ Y, int ldy, int K) {
  constexpr int WM = 2, WN = 2;
  constexpr int FM = BM / WM / 16, FN = BN / WN / 16;
  __shared__ u16 As[BM * 64];
  __shared__ u16 Bs[BN * 64];
  const int tid = threadIdx.x, lane = tid & 63, wid = tid >> 6;
  const int m0 = blockIdx.x * BM, n0 = blockIdx.y * BN;
  const int wm0 = (wid / WN) * (BM / WM), wn0 = (wid % WN) * (BN / WN);

  f32x4 acc[FM][FN] = {};

  for (int kt = 0; kt < K; kt += 64) {
#pragma unroll
    for (int i = 0; i < BM * 8 / 256; i++) {
      int c = i * 256 + tid;
      int r = c >> 3, s = c & 7;
      int ss = s ^ (r & 7);  // pre-swizzled source, linear LDS dest
      gload16(As + c * 8, X + (size_t)(m0 + r) * ldx + kt + ss * 8);
    }
#pragma unroll
    for (int i = 0; i < BN * 8 / 256; i++) {
      int c = i * 256 + tid;
      int r = c >> 3, s = c & 7;
      int ss = s ^ (r & 7);
      gload16(Bs + c * 8, Wt + (size_t)(n0 + r) * K + kt + ss * 8);
    }
    __syncthreads();
#pragma unroll
    for (int kk = 0; kk < 2; kk++) {
      bf16x8 af[FM], bfr[FN];
#pragma unroll
      for (int i = 0; i < FM; i++) {
        int r = wm0 + i * 16 + (lane & 15);
        int q = kk * 4 + (lane >> 4);
        af[i] = *(const bf16x8*)(As + r * 64 + ((q ^ (r & 7)) * 8));
      }
#pragma unroll
      for (int j = 0; j < FN; j++) {
        int r = wn0 + j * 16 + (lane & 15);
        int q = kk * 4 + (lane >> 4);
        bfr[j] = *(const bf16x8*)(Bs + r * 64 + ((q ^ (r & 7)) * 8));
      }
#pragma unroll
      for (int i = 0; i < FM; i++)
#pragma unroll
        for (int j = 0; j < FN; j++)
          acc[i][j] = __builtin_amdgcn_mfma_f32_16x16x32_bf16(af[i], bfr[j], acc[i][j], 0, 0, 0);
    }
    __syncthreads();
  }

  const float* brow = bias + (size_t)(m0 / T_PTS) * bstride;
#pragma unroll
  for (int i = 0; i < FM; i++)
#pragma unroll
    for (int j = 0; j < FN; j++)
#pragma unroll
      for (int r = 0; r < 4; r++) {
        int rl = wm0 + i * 16 + (lane >> 4) * 4 + r;
        int cl = wn0 + j * 16 + (lane & 15);
        float v = acc[i][j][r] + brow[n0 + cl];
        v = fmaxf(v, 0.f);
        Y[(size_t)(m0 + rl) * ldy + n0 + cl] = f2bf(v);
      }
}

// ----------------------------- final heads ---------------------------------
// Rows arrive sorted; scatter to original order via perm.
__global__ __launch_bounds__(256) void final_k(const u16* __restrict__ h2,
                                               const u16* __restrict__ m2,
                                               const float* __restrict__ dw3,
                                               const float* __restrict__ db3,
                                               const float* __restrict__ mw3,
                                               const float* __restrict__ mb3,
                                               const int* __restrict__ perm,
                                               float* __restrict__ out) {
  int m = blockIdx.x * 4 + (threadIdx.x >> 6);
  int lane = threadIdx.x & 63;
  ushort4 hv = *(const ushort4*)(h2 + (size_t)m * 256 + lane * 4);
  float hq[4] = {bf2f(hv.x), bf2f(hv.y), bf2f(hv.z), bf2f(hv.w)};
  float a0 = 0, a1 = 0, a2 = 0, am = 0;
#pragma unroll
  for (int q = 0; q < 4; q++) {
    int k = lane * 4 + q;
    a0 = fmaf(hq[q], dw3[(size_t)k * 3 + 0], a0);
    a1 = fmaf(hq[q], dw3[(size_t)k * 3 + 1], a1);
    a2 = fmaf(hq[q], dw3[(size_t)k * 3 + 2], a2);
  }
  if (lane < 16) {
    ushort4 mv = *(const ushort4*)(m2 + (size_t)m * 64 + lane * 4);
    float mq[4] = {bf2f(mv.x), bf2f(mv.y), bf2f(mv.z), bf2f(mv.w)};
#pragma unroll
    for (int q = 0; q < 4; q++) am = fmaf(mq[q], mw3[lane * 4 + q], am);
  }
#pragma unroll
  for (int off = 32; off > 0; off >>= 1) {
    a0 += __shfl_down(a0, off);
    a1 += __shfl_down(a1, off);
    a2 += __shfl_down(a2, off);
    am += __shfl_down(am, off);
  }
  if (lane == 0) {
    int b = m >> 14;
    int orig = (b << 14) + perm[m];
    out[(size_t)orig * 3 + 0] = a0 + db3[0];
    out[(size_t)orig * 3 + 1] = a1 + db3[1];
    out[(size_t)orig * 3 + 2] = a2 + db3[2];
    float s = am + mb3[0];
    out[DISP_SZ + orig] = 1.f / (1.f + expf(-s));
  }
}

// ------------------------------ launcher -----------------------------------

extern "C" void kernel_launch(void* const* d_in, const int* in_sizes, int n_in,
                              void* d_out, int out_size, void* d_ws, size_t ws_size,
                              hipStream_t stream) {
  const float* tmpl = (const float*)d_in[0];
  const float* sxyz = (const float*)d_in[1];
  const float* gf   = (const float*)d_in[2];
  const float* pf   = (const float*)d_in[3];
  const float* dw1  = (const float*)d_in[4];
  const float* db1  = (const float*)d_in[5];
  const float* dw2  = (const float*)d_in[6];
  const float* db2  = (const float*)d_in[7];
  const float* dw3  = (const float*)d_in[8];
  const float* db3  = (const float*)d_in[9];
  const float* mw1  = (const float*)d_in[10];
  const float* mb1  = (const float*)d_in[11];
  const float* mw2  = (const float*)d_in[12];
  const float* mb2  = (const float*)d_in[13];
  const float* mw3  = (const float*)d_in[14];
  const float* mb3  = (const float*)d_in[15];

  char* ws = (char*)d_ws;
  float4* surfp  = (float4*)(ws + 0);           //   524288 B [4][8192]
  int*    knn    = (int*)(ws + 524288);         //  2097152 B [65536][8]
  u16*    xb     = (u16*)(ws + 2621440);        // 41943040 B [65536][320]
  // alias xb (dead until gather_k):
  float*  part_d = (float*)(ws + 2621440);      //  8388608 B [32][65536]
  int*    part_i = (int*)(ws + 11010048);       //  8388608 B [32][65536]
  u16*    w1t    = (u16*)(ws + 44564480);       //   245760 B [384][320]
  u16*    w2t    = (u16*)(ws + 44810240);       //   131072 B [256][256]
  u16*    w2bt   = (u16*)(ws + 44941312);       //    16384 B [64][128]
  float*  bias1  = (float*)(ws + 44957696);     //     6144 B [4][384]
  u16*    h1     = (u16*)(ws + 44963840);       // 50331648 B [65536][384]
  // alias h1 (dead until gemm1; all consumed by scatter/knn/gather):
  int*    cellb  = (int*)(ws + 44963840);       //   262144 B [65536]
  int*    bins   = (int*)(ws + 45225984);       //   524288 B [4][32768]
  int*    segsum = (int*)(ws + 45750272);       //      256 B [64]
  float4* tmplS  = (float4*)(ws + 45750528);    //  1048576 B [65536]
  u16*    h2     = (u16*)(ws + 95295488);       // 33554432 B [65536][256]
  u16*    m2     = (u16*)(ws + 128849920);      //  8388608 B [65536][64]
  int*    perm   = (int*)(ws + 137238528);      //   262144 B [65536]
  float*  out    = (float*)d_out;

  prep_surf<<<128, 256, 0, stream>>>(sxyz, surfp);
  prep_w<<<768, 256, 0, stream>>>(dw1, mw1, dw2, mw2, w1t, w2t, w2bt);
  bias1_k<<<dim3(B_SZ, 3), 512, 0, stream>>>(gf, dw1, mw1, db1, mb1, bias1);
  zbins_k<<<512, 256, 0, stream>>>(bins);
  hist_t_k<<<256, 256, 0, stream>>>(tmpl, bins, cellb);
  scan1_k<<<64, 1024, 0, stream>>>(bins, segsum);
  scan2_k<<<1, 64, 0, stream>>>(segsum);
  scatter_t_k<<<256, 256, 0, stream>>>(tmpl, cellb, bins, segsum, perm, tmplS);
  knn_part_k<<<dim3(64, NCHUNK, B_SZ), 256, 0, stream>>>(surfp, tmplS, part_d, part_i);
  knn_merge_k<<<256, 256, 0, stream>>>(part_d, part_i, knn);
  gather_k<<<16384, 256, 0, stream>>>(knn, pf, tmplS, xb);
  gemm_k<128, 128><<<dim3(512, 3), 256, 0, stream>>>(xb, K1, w1t, bias1, N1, h1, N1, K1);
  gemm_k<128, 128><<<dim3(512, 2), 256, 0, stream>>>(h1, N1, w2t, db2, 0, h2, 256, 256);
  gemm_k<128, 64><<<dim3(512, 1), 256, 0, stream>>>(h1 + 256, N1, w2bt, mb2, 0, m2, 64, 128);
  final_k<<<16384, 256, 0, stream>>>(h2, m2, dw3, db3, mw3, mb3, perm, out);
}